// Round 5
// baseline (513.564 us; speedup 1.0000x reference)
//
#include <hip/hip_runtime.h>
#include <math.h>

#define SLOPE 0.2f

__device__ __forceinline__ float lrelu(float x) { return x > 0.f ? x : SLOPE * x; }

// bf16 helpers (h is stored bf16 to halve gather traffic; error budget 1e-2)
__device__ __forceinline__ float bflo(unsigned int u) { return __uint_as_float(u << 16); }
__device__ __forceinline__ float bfhi(unsigned int u) { return __uint_as_float(u & 0xffff0000u); }
__device__ __forceinline__ unsigned short f2bf(float f) {   // round-nearest-even
    unsigned int u = __float_as_uint(f);
    unsigned int r = u + 0x7fffu + ((u >> 16) & 1u);
    return (unsigned short)(r >> 16);
}

// ---------------------------------------------------------------------------
// h = x @ W  (CIN=128), fused with attention logits via shfl_xor reduction.
// h written as bf16.
// ---------------------------------------------------------------------------
template <int COUT, int Hh>
__global__ __launch_bounds__(256) void transform_kernel(
    const float* __restrict__ xin, const float* __restrict__ W,
    const float* __restrict__ a_src, const float* __restrict__ a_dst,
    unsigned short* __restrict__ hout, float* __restrict__ alsrc,
    float* __restrict__ aldst, int N)
{
    constexpr int GROUPS = 256 / COUT;   // 2 (COUT=128) or 8 (COUT=32)
    constexpr int NPT = 8;               // nodes per thread
    constexpr int NB = GROUPS * NPT;     // nodes per block: 16 or 64
    __shared__ __align__(16) float xs[NB][128];

    const int node0 = blockIdx.x * NB;
    const int total4 = NB * 128 / 4;
    const float4* src4 = (const float4*)(xin + (size_t)node0 * 128);
    float4* dst4 = (float4*)&xs[0][0];
    int lim4 = (N - node0) * 128 / 4;    // >= total4 unless tail block
    for (int i = threadIdx.x; i < total4; i += 256)
        dst4[i] = (i < lim4) ? src4[i] : make_float4(0.f, 0.f, 0.f, 0.f);
    __syncthreads();

    const int j = threadIdx.x % COUT;
    const int g = threadIdx.x / COUT;
    const int hh = j >> 5;               // head (Cc = 32)
    const int jl = j & 31;               // lane within head
    const float as = a_src[hh * 32 + jl];
    const float ad = a_dst[hh * 32 + jl];

    float acc[NPT];
#pragma unroll
    for (int m = 0; m < NPT; ++m) acc[m] = 0.f;

    for (int k = 0; k < 128; ++k) {
        float w = W[k * COUT + j];
#pragma unroll
        for (int m = 0; m < NPT; ++m) acc[m] += xs[g * NPT + m][k] * w;
    }

#pragma unroll
    for (int m = 0; m < NPT; ++m) {
        int n = node0 + g * NPT + m;
        float v = acc[m];
        float sv = v * as, dv = v * ad;
#pragma unroll
        for (int off = 16; off >= 1; off >>= 1) {
            sv += __shfl_xor(sv, off);
            dv += __shfl_xor(dv, off);
        }
        if (n < N) {
            hout[(size_t)n * COUT + j] = f2bf(v);
            if (jl == 0) {
                alsrc[n * Hh + hh] = sv;
                aldst[n * Hh + hh] = dv;
            }
        }
    }
}

// ---------------------------------------------------------------------------
// CSR build, bucket-local counting sort (64 dst nodes per bucket):
//   bin   : b = dst>>6, tmp[b][cursor++] = src<<6 | dst&63  (L2-local writes)
//   hist  : per-bucket LDS histogram -> deg[] (coalesced, no global atomics)
//   scan  : 3-pass multi-block exclusive scan of deg -> offsets
//   place : per-bucket LDS cursors seeded from offsets -> src_sorted
// ---------------------------------------------------------------------------
#define BKT_CAP 2048   // bucket capacity (E/N*64 ~= 1024 expected, 32 sigma)

__global__ __launch_bounds__(256) void bin_kernel(
    const int* __restrict__ src, const int* __restrict__ dst,
    int* __restrict__ bcnt, unsigned int* __restrict__ tmp, int E)
{
    int e = blockIdx.x * 256 + threadIdx.x;
    if (e >= E) return;
    int d = dst[e];
    int b = d >> 6;
    int pos = atomicAdd(&bcnt[b], 1);
    if (pos < BKT_CAP)
        tmp[((size_t)b << 11) + pos] = ((unsigned int)src[e] << 6) | (unsigned int)(d & 63);
}

__global__ __launch_bounds__(256) void hist_kernel(
    const unsigned int* __restrict__ tmp, const int* __restrict__ bcnt,
    int* __restrict__ deg, int N)
{
    int b = blockIdx.x;
    __shared__ int hist[64];
    if (threadIdx.x < 64) hist[threadIdx.x] = 0;
    __syncthreads();
    int cnt = min(bcnt[b], BKT_CAP);
    const unsigned int* tb = tmp + ((size_t)b << 11);
    for (int i = threadIdx.x; i < cnt; i += 256)
        atomicAdd(&hist[tb[i] & 63u], 1);
    __syncthreads();
    if (threadIdx.x < 64) {
        int node = (b << 6) + threadIdx.x;
        if (node < N) deg[node] = hist[threadIdx.x];
    }
}

__global__ __launch_bounds__(256) void block_sum_kernel(
    const int* __restrict__ deg, int* __restrict__ blocksums, int N)
{
    int base = blockIdx.x * 4096 + threadIdx.x * 16;
    int s = 0;
#pragma unroll
    for (int i = 0; i < 16; ++i) {
        int idx = base + i;
        if (idx < N) s += deg[idx];
    }
#pragma unroll
    for (int off = 1; off < 64; off <<= 1) s += __shfl_xor(s, off);
    __shared__ int wsum[4];
    if ((threadIdx.x & 63) == 0) wsum[threadIdx.x >> 6] = s;
    __syncthreads();
    if (threadIdx.x == 0)
        blocksums[blockIdx.x] = wsum[0] + wsum[1] + wsum[2] + wsum[3];
}

__global__ __launch_bounds__(64) void scan_sums_kernel(
    const int* __restrict__ blocksums, int* __restrict__ blockbase,
    int* __restrict__ total_out, int nb)
{
    int tid = threadIdx.x;
    int orig = (tid < nb) ? blocksums[tid] : 0;
    int v = orig;
#pragma unroll
    for (int off = 1; off < 64; off <<= 1) {
        int t = __shfl_up(v, off);
        if (tid >= off) v += t;
    }
    if (tid < nb) blockbase[tid] = v - orig;     // exclusive
    if (tid == nb - 1) *total_out = v;           // offsets[N]
}

__global__ __launch_bounds__(256) void scan_final_kernel(
    const int* __restrict__ deg, const int* __restrict__ blockbase,
    int* __restrict__ offsets, int N)
{
    int base = blockIdx.x * 4096 + threadIdx.x * 16;
    int v[16];
    int s = 0;
#pragma unroll
    for (int i = 0; i < 16; ++i) {
        int idx = base + i;
        v[i] = (idx < N) ? deg[idx] : 0;
        s += v[i];
    }
    int lane = threadIdx.x & 63, wid = threadIdx.x >> 6;
    int incl = s;
#pragma unroll
    for (int off = 1; off < 64; off <<= 1) {
        int t = __shfl_up(incl, off);
        if (lane >= off) incl += t;
    }
    __shared__ int wsum[4];
    if (lane == 63) wsum[wid] = incl;
    __syncthreads();
    int woff = 0;
    for (int i = 0; i < wid; ++i) woff += wsum[i];
    int run = blockbase[blockIdx.x] + woff + incl - s;  // thread-exclusive
#pragma unroll
    for (int i = 0; i < 16; ++i) {
        int idx = base + i;
        if (idx < N) offsets[idx] = run;
        run += v[i];
    }
}

__global__ __launch_bounds__(256) void place_kernel(
    const unsigned int* __restrict__ tmp, const int* __restrict__ bcnt,
    const int* __restrict__ offsets, int* __restrict__ src_sorted, int N)
{
    int b = blockIdx.x;
    __shared__ int cur[64];
    if (threadIdx.x < 64) {
        int node = (b << 6) + threadIdx.x;
        cur[threadIdx.x] = (node < N) ? offsets[node] : 0;
    }
    __syncthreads();
    int cnt = min(bcnt[b], BKT_CAP);
    const unsigned int* tb = tmp + ((size_t)b << 11);
    for (int i = threadIdx.x; i < cnt; i += 256) {
        unsigned int p = tb[i];
        int pos = atomicAdd(&cur[p & 63u], 1);
        src_sorted[pos] = (int)(p >> 6);
    }
}

// ---------------------------------------------------------------------------
// Fused GAT aggregation (per-node gather, zero atomics), bf16 h:
// 4 channels per thread (one 8B load per edge/thread), TPN = HC/4 threads
// per node. Edge weights staged in LDS per chunk; denominator in-register;
// self-loop folded analytically; divide, +bias, (ELU).
// ---------------------------------------------------------------------------
template <int Hh, int Cc, bool DO_ELU>
__global__ __launch_bounds__(256) void gat_agg_kernel(
    const int* __restrict__ offsets, const int* __restrict__ src_sorted,
    const unsigned short* __restrict__ h, const float* __restrict__ alsrc,
    const float* __restrict__ aldst, const float* __restrict__ bias,
    float* __restrict__ outf, int N)
{
    constexpr int HC  = Hh * Cc;         // 128 or 32
    constexpr int TPN = HC / 4;          // threads per node: 32 or 8
    constexpr int NPB = 256 / TPN;       // nodes per block: 8 or 32
    constexpr int CHUNK = 64;
    __shared__ int   s_src[NPB][CHUNK];
    __shared__ __align__(16) float s_w[NPB][CHUNK][Hh];
    __shared__ int   s_nch[NPB];

    const int g  = threadIdx.x / TPN;
    const int lt = threadIdx.x % TPN;
    const int n  = blockIdx.x * NPB + g;
    const bool valid = n < N;

    int off0 = 0, deg = 0;
    if (valid) { off0 = offsets[n]; deg = offsets[n + 1] - off0; }
    if (lt == 0) s_nch[g] = (deg + CHUNK - 1) / CHUNK;
    __syncthreads();
    int maxch = 0;
#pragma unroll
    for (int i = 0; i < NPB; ++i) maxch = max(maxch, s_nch[i]);

    const int hh = lt / (Cc / 4);        // head of this thread's 4 channels
    float adv[Hh];
    if (valid) {
        if constexpr (Hh == 4) {
            float4 t = ((const float4*)aldst)[n];
            adv[0] = t.x; adv[1] = t.y; adv[2] = t.z; adv[3] = t.w;
        } else {
            adv[0] = aldst[n];
        }
    }

    const uint2* h2 = (const uint2*)h;   // one row = TPN uint2 (8B = 4 ch)

    float a0 = 0.f, a1 = 0.f, a2 = 0.f, a3 = 0.f, den = 0.f;
    for (int ch = 0; ch < maxch; ++ch) {
        int base = ch * CHUNK;
        int cnt = deg - base;
        cnt = cnt < 0 ? 0 : (cnt > CHUNK ? CHUNK : cnt);
        __syncthreads();                 // LDS reuse fence
        for (int i = lt; i < cnt; i += TPN) {
            int s = src_sorted[off0 + base + i];
            s_src[g][i] = s;
            if constexpr (Hh == 4) {
                float4 av = ((const float4*)alsrc)[s];
                ((float4*)&s_w[g][i][0])[0] = make_float4(
                    __expf(lrelu(av.x + adv[0])), __expf(lrelu(av.y + adv[1])),
                    __expf(lrelu(av.z + adv[2])), __expf(lrelu(av.w + adv[3])));
            } else {
                s_w[g][i][0] = __expf(lrelu(alsrc[s] + adv[0]));
            }
        }
        __syncthreads();
        for (int i = 0; i < cnt; ++i) {
            int s = s_src[g][i];
            float w = s_w[g][i][hh];
            uint2 p = h2[(size_t)s * TPN + lt];
            a0 += w * bflo(p.x);
            a1 += w * bfhi(p.x);
            a2 += w * bflo(p.y);
            a3 += w * bfhi(p.y);
            den += w;
        }
    }

    if (valid) {
        float wself = __expf(lrelu(alsrc[n * Hh + hh] + adv[hh]));
        uint2 p = h2[(size_t)n * TPN + lt];
        a0 += wself * bflo(p.x);
        a1 += wself * bfhi(p.x);
        a2 += wself * bflo(p.y);
        a3 += wself * bfhi(p.y);
        den += wself + 1e-16f;
        float inv = 1.f / den;
        float4 bv = ((const float4*)bias)[lt];
        float4 o = make_float4(a0 * inv + bv.x, a1 * inv + bv.y,
                               a2 * inv + bv.z, a3 * inv + bv.w);
        if (DO_ELU) {
            o.x = o.x > 0.f ? o.x : __expf(o.x) - 1.f;
            o.y = o.y > 0.f ? o.y : __expf(o.y) - 1.f;
            o.z = o.z > 0.f ? o.z : __expf(o.z) - 1.f;
            o.w = o.w > 0.f ? o.w : __expf(o.w) - 1.f;
        }
        ((float4*)(outf + (size_t)n * HC))[lt] = o;
    }
}

// ---------------------------------------------------------------------------
// classification head: out[n,k] = h3[n,:] @ Wc[:,k] + bc[k]   (32 -> 2)
// ---------------------------------------------------------------------------
__global__ __launch_bounds__(256) void head_kernel(
    const float* __restrict__ h3, const float* __restrict__ Wc,
    const float* __restrict__ bc, float* __restrict__ out, int N)
{
    int t = blockIdx.x * 256 + threadIdx.x;
    int n = t / 2, k = t % 2;
    if (n >= N) return;
    float s = bc[k];
#pragma unroll
    for (int c = 0; c < 32; ++c) s += h3[(size_t)n * 32 + c] * Wc[c * 2 + k];
    out[(size_t)n * 2 + k] = s;
}

extern "C" void kernel_launch(void* const* d_in, const int* in_sizes, int n_in,
                              void* d_out, int out_size, void* d_ws, size_t ws_size,
                              hipStream_t stream)
{
    const float* x   = (const float*)d_in[0];
    const int*   ei  = (const int*)d_in[1];
    const float* W1  = (const float*)d_in[2];
    const float* a1s = (const float*)d_in[3];
    const float* a1d = (const float*)d_in[4];
    const float* b1  = (const float*)d_in[5];
    const float* W2  = (const float*)d_in[6];
    const float* a2s = (const float*)d_in[7];
    const float* a2d = (const float*)d_in[8];
    const float* b2  = (const float*)d_in[9];
    const float* W3  = (const float*)d_in[10];
    const float* a3s = (const float*)d_in[11];
    const float* a3d = (const float*)d_in[12];
    const float* b3  = (const float*)d_in[13];
    const float* Wc  = (const float*)d_in[14];
    const float* bc  = (const float*)d_in[15];

    const int N = in_sizes[0] / 128;
    const int E = in_sizes[1] / 2;
    const int* srcIdx = ei;
    const int* dstIdx = ei + E;

    const int NBKT = (N + 63) >> 6;                     // buckets of 64 dsts

    float* ws    = (float*)d_ws;
    float* fbuf  = ws;                                  // N*128 fp32
    float* alsrc = fbuf + (size_t)N * 128;              // N*4 (16B aligned)
    float* aldst = alsrc + (size_t)N * 4;               // N*4
    unsigned short* hbuf = (unsigned short*)(aldst + (size_t)N * 4); // N*128 bf16
    int* deg        = (int*)(hbuf + (size_t)N * 128);   // N
    int* offsets    = deg + N;                          // N+1
    int* src_sorted = offsets + N + 1;                  // E
    int* blocksums  = src_sorted + E;                   // 64
    int* blockbase  = blocksums + 64;                   // 64
    int* bcnt       = blockbase + 64;                   // NBKT
    unsigned int* tmp = (unsigned int*)(bcnt + NBKT);   // NBKT * BKT_CAP

    float* node_out = (float*)d_out;                    // N*2
    float* link_out = node_out + (size_t)N * 2;         // N*32

    const int gridE = (E + 255) / 256;
    const int nb = (N + 4095) / 4096;                   // scan blocks (<=64)

    // ---------------- CSR build (dst-sorted), reused by all 3 layers --------
    hipMemsetAsync(bcnt, 0, (size_t)NBKT * sizeof(int), stream);
    bin_kernel<<<gridE, 256, 0, stream>>>(srcIdx, dstIdx, bcnt, tmp, E);
    hist_kernel<<<NBKT, 256, 0, stream>>>(tmp, bcnt, deg, N);
    block_sum_kernel<<<nb, 256, 0, stream>>>(deg, blocksums, N);
    scan_sums_kernel<<<1, 64, 0, stream>>>(blocksums, blockbase, offsets + N, nb);
    scan_final_kernel<<<nb, 256, 0, stream>>>(deg, blockbase, offsets, N);
    place_kernel<<<NBKT, 256, 0, stream>>>(tmp, bcnt, offsets, src_sorted, N);

    // ---------------- layer 1 (IN=128 -> H=4,C=32, concat, ELU) -------------
    transform_kernel<128, 4><<<(N + 15) / 16, 256, 0, stream>>>(
        x, W1, a1s, a1d, hbuf, alsrc, aldst, N);
    gat_agg_kernel<4, 32, true><<<(N + 7) / 8, 256, 0, stream>>>(
        offsets, src_sorted, hbuf, alsrc, aldst, b1, fbuf, N);

    // ---------------- layer 2 (128 -> H=4,C=32, concat, ELU) ----------------
    transform_kernel<128, 4><<<(N + 15) / 16, 256, 0, stream>>>(
        fbuf, W2, a2s, a2d, hbuf, alsrc, aldst, N);
    gat_agg_kernel<4, 32, true><<<(N + 7) / 8, 256, 0, stream>>>(
        offsets, src_sorted, hbuf, alsrc, aldst, b2, fbuf, N);

    // ---------------- layer 3 (128 -> H=1,C=32, no concat, no ELU) ----------
    transform_kernel<32, 1><<<(N + 63) / 64, 256, 0, stream>>>(
        fbuf, W3, a3s, a3d, hbuf, alsrc, aldst, N);
    gat_agg_kernel<1, 32, false><<<(N + 31) / 32, 256, 0, stream>>>(
        offsets, src_sorted, hbuf, alsrc, aldst, b3, link_out, N);

    // ---------------- head: node_output = h3 @ Wc + bc ----------------------
    head_kernel<<<(N * 2 + 255) / 256, 256, 0, stream>>>(link_out, Wc, bc, node_out, N);
}

// Round 6
// 368.448 us; speedup vs baseline: 1.3939x; 1.3939x over previous
//
#include <hip/hip_runtime.h>
#include <math.h>

#define SLOPE 0.2f

__device__ __forceinline__ float lrelu(float x) { return x > 0.f ? x : SLOPE * x; }

// bf16 helpers (h is stored bf16 to halve gather traffic; error budget 1e-2)
__device__ __forceinline__ float bflo(unsigned int u) { return __uint_as_float(u << 16); }
__device__ __forceinline__ float bfhi(unsigned int u) { return __uint_as_float(u & 0xffff0000u); }
__device__ __forceinline__ unsigned short f2bf(float f) {   // round-nearest-even
    unsigned int u = __float_as_uint(f);
    unsigned int r = u + 0x7fffu + ((u >> 16) & 1u);
    return (unsigned short)(r >> 16);
}

// ---------------------------------------------------------------------------
// h = x @ W  (CIN=128), fused with attention logits via shfl_xor reduction.
// h written as bf16.
// ---------------------------------------------------------------------------
template <int COUT, int Hh>
__global__ __launch_bounds__(256) void transform_kernel(
    const float* __restrict__ xin, const float* __restrict__ W,
    const float* __restrict__ a_src, const float* __restrict__ a_dst,
    unsigned short* __restrict__ hout, float* __restrict__ alsrc,
    float* __restrict__ aldst, int N)
{
    constexpr int GROUPS = 256 / COUT;   // 2 (COUT=128) or 8 (COUT=32)
    constexpr int NPT = 8;               // nodes per thread
    constexpr int NB = GROUPS * NPT;     // nodes per block: 16 or 64
    __shared__ __align__(16) float xs[NB][128];

    const int node0 = blockIdx.x * NB;
    const int total4 = NB * 128 / 4;
    const float4* src4 = (const float4*)(xin + (size_t)node0 * 128);
    float4* dst4 = (float4*)&xs[0][0];
    int lim4 = (N - node0) * 128 / 4;    // >= total4 unless tail block
    for (int i = threadIdx.x; i < total4; i += 256)
        dst4[i] = (i < lim4) ? src4[i] : make_float4(0.f, 0.f, 0.f, 0.f);
    __syncthreads();

    const int j = threadIdx.x % COUT;
    const int g = threadIdx.x / COUT;
    const int hh = j >> 5;               // head (Cc = 32)
    const int jl = j & 31;               // lane within head
    const float as = a_src[hh * 32 + jl];
    const float ad = a_dst[hh * 32 + jl];

    float acc[NPT];
#pragma unroll
    for (int m = 0; m < NPT; ++m) acc[m] = 0.f;

    for (int k = 0; k < 128; ++k) {
        float w = W[k * COUT + j];
#pragma unroll
        for (int m = 0; m < NPT; ++m) acc[m] += xs[g * NPT + m][k] * w;
    }

#pragma unroll
    for (int m = 0; m < NPT; ++m) {
        int n = node0 + g * NPT + m;
        float v = acc[m];
        float sv = v * as, dv = v * ad;
#pragma unroll
        for (int off = 16; off >= 1; off >>= 1) {
            sv += __shfl_xor(sv, off);
            dv += __shfl_xor(dv, off);
        }
        if (n < N) {
            hout[(size_t)n * COUT + j] = f2bf(v);
            if (jl == 0) {
                alsrc[n * Hh + hh] = sv;
                aldst[n * Hh + hh] = dv;
            }
        }
    }
}

// ---------------------------------------------------------------------------
// CSR build, bucket-local counting sort (64 dst nodes per bucket):
//   bin   : block-aggregated — LDS histogram over buckets, ONE padded global
//           atomic per (block,bucket) run reservation, LDS-cursor placement.
//           Runs are ~42B contiguous -> near-full-line writebacks.
//   hist  : per-bucket LDS histogram -> deg[] (coalesced)
//   scan  : 3-pass multi-block exclusive scan of deg -> offsets
//   place : per-bucket LDS cursors seeded from offsets -> src_sorted
//           (all writes of a bucket land in one ~4KB region from one block)
// ---------------------------------------------------------------------------
#define BKT_CAP 2048    // slots per bucket (E/N*64 ~= 1023 expected)
#define NBKT_MAX 1024   // supports N <= 65536
#define CH_BIN 8192     // edges per bin block

__global__ __launch_bounds__(256) void bin_kernel(
    const int* __restrict__ src, const int* __restrict__ dst,
    int* __restrict__ bcnt, unsigned int* __restrict__ tmp, int E, int nbkt)
{
    __shared__ int hist[NBKT_MAX];
    __shared__ int base[NBKT_MAX];
    const int e0 = blockIdx.x * CH_BIN;
    const int e1 = min(e0 + CH_BIN, E);

    for (int b = threadIdx.x; b < nbkt; b += 256) hist[b] = 0;
    __syncthreads();
    for (int e = e0 + threadIdx.x; e < e1; e += 256) {
        int d = __builtin_nontemporal_load(dst + e);
        atomicAdd(&hist[d >> 6], 1);
    }
    __syncthreads();
    for (int b = threadIdx.x; b < nbkt; b += 256) {
        int c = hist[b];
        base[b] = (c > 0) ? atomicAdd(&bcnt[b << 4], c) : 0;  // 64B-strided
        hist[b] = 0;                                          // reuse as cursor
    }
    __syncthreads();
    for (int e = e0 + threadIdx.x; e < e1; e += 256) {
        int d = __builtin_nontemporal_load(dst + e);
        int s = __builtin_nontemporal_load(src + e);
        int b = d >> 6;
        int pos = base[b] + atomicAdd(&hist[b], 1);
        if (pos < BKT_CAP)
            tmp[((size_t)b << 11) + pos] =
                ((unsigned int)s << 6) | (unsigned int)(d & 63);
    }
}

__global__ __launch_bounds__(256) void hist_kernel(
    const unsigned int* __restrict__ tmp, const int* __restrict__ bcnt,
    int* __restrict__ deg, int N)
{
    int b = blockIdx.x;
    __shared__ int hist[64];
    if (threadIdx.x < 64) hist[threadIdx.x] = 0;
    __syncthreads();
    int cnt = min(bcnt[b << 4], BKT_CAP);
    const unsigned int* tb = tmp + ((size_t)b << 11);
    for (int i = threadIdx.x; i < cnt; i += 256)
        atomicAdd(&hist[tb[i] & 63u], 1);
    __syncthreads();
    if (threadIdx.x < 64) {
        int node = (b << 6) + threadIdx.x;
        if (node < N) deg[node] = hist[threadIdx.x];
    }
}

__global__ __launch_bounds__(256) void block_sum_kernel(
    const int* __restrict__ deg, int* __restrict__ blocksums, int N)
{
    int base = blockIdx.x * 4096 + threadIdx.x * 16;
    int s = 0;
#pragma unroll
    for (int i = 0; i < 16; ++i) {
        int idx = base + i;
        if (idx < N) s += deg[idx];
    }
#pragma unroll
    for (int off = 1; off < 64; off <<= 1) s += __shfl_xor(s, off);
    __shared__ int wsum[4];
    if ((threadIdx.x & 63) == 0) wsum[threadIdx.x >> 6] = s;
    __syncthreads();
    if (threadIdx.x == 0)
        blocksums[blockIdx.x] = wsum[0] + wsum[1] + wsum[2] + wsum[3];
}

__global__ __launch_bounds__(64) void scan_sums_kernel(
    const int* __restrict__ blocksums, int* __restrict__ blockbase,
    int* __restrict__ total_out, int nb)
{
    int tid = threadIdx.x;
    int orig = (tid < nb) ? blocksums[tid] : 0;
    int v = orig;
#pragma unroll
    for (int off = 1; off < 64; off <<= 1) {
        int t = __shfl_up(v, off);
        if (tid >= off) v += t;
    }
    if (tid < nb) blockbase[tid] = v - orig;     // exclusive
    if (tid == nb - 1) *total_out = v;           // offsets[N]
}

__global__ __launch_bounds__(256) void scan_final_kernel(
    const int* __restrict__ deg, const int* __restrict__ blockbase,
    int* __restrict__ offsets, int N)
{
    int base = blockIdx.x * 4096 + threadIdx.x * 16;
    int v[16];
    int s = 0;
#pragma unroll
    for (int i = 0; i < 16; ++i) {
        int idx = base + i;
        v[i] = (idx < N) ? deg[idx] : 0;
        s += v[i];
    }
    int lane = threadIdx.x & 63, wid = threadIdx.x >> 6;
    int incl = s;
#pragma unroll
    for (int off = 1; off < 64; off <<= 1) {
        int t = __shfl_up(incl, off);
        if (lane >= off) incl += t;
    }
    __shared__ int wsum[4];
    if (lane == 63) wsum[wid] = incl;
    __syncthreads();
    int woff = 0;
    for (int i = 0; i < wid; ++i) woff += wsum[i];
    int run = blockbase[blockIdx.x] + woff + incl - s;  // thread-exclusive
#pragma unroll
    for (int i = 0; i < 16; ++i) {
        int idx = base + i;
        if (idx < N) offsets[idx] = run;
        run += v[i];
    }
}

__global__ __launch_bounds__(256) void place_kernel(
    const unsigned int* __restrict__ tmp, const int* __restrict__ bcnt,
    const int* __restrict__ offsets, int* __restrict__ src_sorted, int N)
{
    int b = blockIdx.x;
    __shared__ int cur[64];
    if (threadIdx.x < 64) {
        int node = (b << 6) + threadIdx.x;
        cur[threadIdx.x] = (node < N) ? offsets[node] : 0;
    }
    __syncthreads();
    int cnt = min(bcnt[b << 4], BKT_CAP);
    const unsigned int* tb = tmp + ((size_t)b << 11);
    for (int i = threadIdx.x; i < cnt; i += 256) {
        unsigned int p = tb[i];
        int pos = atomicAdd(&cur[p & 63u], 1);
        src_sorted[pos] = (int)(p >> 6);
    }
}

// ---------------------------------------------------------------------------
// Fused GAT aggregation (per-node gather, zero atomics), bf16 h:
// 4 channels per thread (one 8B load per edge/thread), TPN = HC/4 threads
// per node. Edge weights staged in LDS per chunk; denominator in-register;
// self-loop folded analytically; divide, +bias, (ELU).
// ---------------------------------------------------------------------------
template <int Hh, int Cc, bool DO_ELU>
__global__ __launch_bounds__(256) void gat_agg_kernel(
    const int* __restrict__ offsets, const int* __restrict__ src_sorted,
    const unsigned short* __restrict__ h, const float* __restrict__ alsrc,
    const float* __restrict__ aldst, const float* __restrict__ bias,
    float* __restrict__ outf, int N)
{
    constexpr int HC  = Hh * Cc;         // 128 or 32
    constexpr int TPN = HC / 4;          // threads per node: 32 or 8
    constexpr int NPB = 256 / TPN;       // nodes per block: 8 or 32
    constexpr int CHUNK = 64;
    __shared__ int   s_src[NPB][CHUNK];
    __shared__ __align__(16) float s_w[NPB][CHUNK][Hh];
    __shared__ int   s_nch[NPB];

    const int g  = threadIdx.x / TPN;
    const int lt = threadIdx.x % TPN;
    const int n  = blockIdx.x * NPB + g;
    const bool valid = n < N;

    int off0 = 0, deg = 0;
    if (valid) { off0 = offsets[n]; deg = offsets[n + 1] - off0; }
    if (lt == 0) s_nch[g] = (deg + CHUNK - 1) / CHUNK;
    __syncthreads();
    int maxch = 0;
#pragma unroll
    for (int i = 0; i < NPB; ++i) maxch = max(maxch, s_nch[i]);

    const int hh = lt / (Cc / 4);        // head of this thread's 4 channels
    float adv[Hh];
    if (valid) {
        if constexpr (Hh == 4) {
            float4 t = ((const float4*)aldst)[n];
            adv[0] = t.x; adv[1] = t.y; adv[2] = t.z; adv[3] = t.w;
        } else {
            adv[0] = aldst[n];
        }
    }

    const uint2* h2 = (const uint2*)h;   // one row = TPN uint2 (8B = 4 ch)

    float a0 = 0.f, a1 = 0.f, a2 = 0.f, a3 = 0.f, den = 0.f;
    for (int ch = 0; ch < maxch; ++ch) {
        int base = ch * CHUNK;
        int cnt = deg - base;
        cnt = cnt < 0 ? 0 : (cnt > CHUNK ? CHUNK : cnt);
        __syncthreads();                 // LDS reuse fence
        for (int i = lt; i < cnt; i += TPN) {
            int s = src_sorted[off0 + base + i];
            s_src[g][i] = s;
            if constexpr (Hh == 4) {
                float4 av = ((const float4*)alsrc)[s];
                ((float4*)&s_w[g][i][0])[0] = make_float4(
                    __expf(lrelu(av.x + adv[0])), __expf(lrelu(av.y + adv[1])),
                    __expf(lrelu(av.z + adv[2])), __expf(lrelu(av.w + adv[3])));
            } else {
                s_w[g][i][0] = __expf(lrelu(alsrc[s] + adv[0]));
            }
        }
        __syncthreads();
        for (int i = 0; i < cnt; ++i) {
            int s = s_src[g][i];
            float w = s_w[g][i][hh];
            uint2 p = h2[(size_t)s * TPN + lt];
            a0 += w * bflo(p.x);
            a1 += w * bfhi(p.x);
            a2 += w * bflo(p.y);
            a3 += w * bfhi(p.y);
            den += w;
        }
    }

    if (valid) {
        float wself = __expf(lrelu(alsrc[n * Hh + hh] + adv[hh]));
        uint2 p = h2[(size_t)n * TPN + lt];
        a0 += wself * bflo(p.x);
        a1 += wself * bfhi(p.x);
        a2 += wself * bflo(p.y);
        a3 += wself * bfhi(p.y);
        den += wself + 1e-16f;
        float inv = 1.f / den;
        float4 bv = ((const float4*)bias)[lt];
        float4 o = make_float4(a0 * inv + bv.x, a1 * inv + bv.y,
                               a2 * inv + bv.z, a3 * inv + bv.w);
        if (DO_ELU) {
            o.x = o.x > 0.f ? o.x : __expf(o.x) - 1.f;
            o.y = o.y > 0.f ? o.y : __expf(o.y) - 1.f;
            o.z = o.z > 0.f ? o.z : __expf(o.z) - 1.f;
            o.w = o.w > 0.f ? o.w : __expf(o.w) - 1.f;
        }
        ((float4*)(outf + (size_t)n * HC))[lt] = o;
    }
}

// ---------------------------------------------------------------------------
// classification head: out[n,k] = h3[n,:] @ Wc[:,k] + bc[k]   (32 -> 2)
// ---------------------------------------------------------------------------
__global__ __launch_bounds__(256) void head_kernel(
    const float* __restrict__ h3, const float* __restrict__ Wc,
    const float* __restrict__ bc, float* __restrict__ out, int N)
{
    int t = blockIdx.x * 256 + threadIdx.x;
    int n = t / 2, k = t % 2;
    if (n >= N) return;
    float s = bc[k];
#pragma unroll
    for (int c = 0; c < 32; ++c) s += h3[(size_t)n * 32 + c] * Wc[c * 2 + k];
    out[(size_t)n * 2 + k] = s;
}

extern "C" void kernel_launch(void* const* d_in, const int* in_sizes, int n_in,
                              void* d_out, int out_size, void* d_ws, size_t ws_size,
                              hipStream_t stream)
{
    const float* x   = (const float*)d_in[0];
    const int*   ei  = (const int*)d_in[1];
    const float* W1  = (const float*)d_in[2];
    const float* a1s = (const float*)d_in[3];
    const float* a1d = (const float*)d_in[4];
    const float* b1  = (const float*)d_in[5];
    const float* W2  = (const float*)d_in[6];
    const float* a2s = (const float*)d_in[7];
    const float* a2d = (const float*)d_in[8];
    const float* b2  = (const float*)d_in[9];
    const float* W3  = (const float*)d_in[10];
    const float* a3s = (const float*)d_in[11];
    const float* a3d = (const float*)d_in[12];
    const float* b3  = (const float*)d_in[13];
    const float* Wc  = (const float*)d_in[14];
    const float* bc  = (const float*)d_in[15];

    const int N = in_sizes[0] / 128;
    const int E = in_sizes[1] / 2;
    const int* srcIdx = ei;
    const int* dstIdx = ei + E;

    const int NBKT = (N + 63) >> 6;                     // buckets of 64 dsts

    float* ws    = (float*)d_ws;
    float* fbuf  = ws;                                  // N*128 fp32
    float* alsrc = fbuf + (size_t)N * 128;              // N*4 (16B aligned)
    float* aldst = alsrc + (size_t)N * 4;               // N*4
    unsigned short* hbuf = (unsigned short*)(aldst + (size_t)N * 4); // N*128 bf16
    int* deg        = (int*)(hbuf + (size_t)N * 128);   // N
    int* offsets    = deg + N;                          // N+1
    int* src_sorted = offsets + N + 1;                  // E
    int* blocksums  = src_sorted + E;                   // 64
    int* blockbase  = blocksums + 64;                   // 64
    int* bcnt       = blockbase + 64;                   // NBKT*16 (64B-strided)
    unsigned int* tmp = (unsigned int*)(bcnt + (size_t)NBKT * 16); // NBKT*BKT_CAP

    float* node_out = (float*)d_out;                    // N*2
    float* link_out = node_out + (size_t)N * 2;         // N*32

    const int nb = (N + 4095) / 4096;                   // scan blocks (<=64)
    const int nbBin = (E + CH_BIN - 1) / CH_BIN;

    // ---------------- CSR build (dst-sorted), reused by all 3 layers --------
    hipMemsetAsync(bcnt, 0, (size_t)NBKT * 16 * sizeof(int), stream);
    bin_kernel<<<nbBin, 256, 0, stream>>>(srcIdx, dstIdx, bcnt, tmp, E, NBKT);
    hist_kernel<<<NBKT, 256, 0, stream>>>(tmp, bcnt, deg, N);
    block_sum_kernel<<<nb, 256, 0, stream>>>(deg, blocksums, N);
    scan_sums_kernel<<<1, 64, 0, stream>>>(blocksums, blockbase, offsets + N, nb);
    scan_final_kernel<<<nb, 256, 0, stream>>>(deg, blockbase, offsets, N);
    place_kernel<<<NBKT, 256, 0, stream>>>(tmp, bcnt, offsets, src_sorted, N);

    // ---------------- layer 1 (IN=128 -> H=4,C=32, concat, ELU) -------------
    transform_kernel<128, 4><<<(N + 15) / 16, 256, 0, stream>>>(
        x, W1, a1s, a1d, hbuf, alsrc, aldst, N);
    gat_agg_kernel<4, 32, true><<<(N + 7) / 8, 256, 0, stream>>>(
        offsets, src_sorted, hbuf, alsrc, aldst, b1, fbuf, N);

    // ---------------- layer 2 (128 -> H=4,C=32, concat, ELU) ----------------
    transform_kernel<128, 4><<<(N + 15) / 16, 256, 0, stream>>>(
        fbuf, W2, a2s, a2d, hbuf, alsrc, aldst, N);
    gat_agg_kernel<4, 32, true><<<(N + 7) / 8, 256, 0, stream>>>(
        offsets, src_sorted, hbuf, alsrc, aldst, b2, fbuf, N);

    // ---------------- layer 3 (128 -> H=1,C=32, no concat, no ELU) ----------
    transform_kernel<32, 1><<<(N + 63) / 64, 256, 0, stream>>>(
        fbuf, W3, a3s, a3d, hbuf, alsrc, aldst, N);
    gat_agg_kernel<1, 32, false><<<(N + 31) / 32, 256, 0, stream>>>(
        offsets, src_sorted, hbuf, alsrc, aldst, b3, link_out, N);

    // ---------------- head: node_output = h3 @ Wc + bc ----------------------
    head_kernel<<<(N * 2 + 255) / 256, 256, 0, stream>>>(link_out, Wc, bc, node_out, N);
}

// Round 7
// 348.381 us; speedup vs baseline: 1.4741x; 1.0576x over previous
//
#include <hip/hip_runtime.h>
#include <math.h>

#define SLOPE 0.2f

__device__ __forceinline__ float lrelu(float x) { return x > 0.f ? x : SLOPE * x; }

// bf16 helpers (h is stored bf16 to halve gather traffic; error budget 1e-2)
__device__ __forceinline__ float bflo(unsigned int u) { return __uint_as_float(u << 16); }
__device__ __forceinline__ float bfhi(unsigned int u) { return __uint_as_float(u & 0xffff0000u); }
__device__ __forceinline__ unsigned short f2bf(float f) {   // round-nearest-even
    unsigned int u = __float_as_uint(f);
    unsigned int r = u + 0x7fffu + ((u >> 16) & 1u);
    return (unsigned short)(r >> 16);
}

// ---------------------------------------------------------------------------
// h = x @ W  (CIN=128), fused with attention logits.
// Register tile: 4 output channels x NPT nodes per thread (k4-vectorized:
// ds_read_b128 for x, dwordx4 for W, VALU-bound ~86% FMA density).
// Logits via 3-step shfl_xor over the 8 threads of each head.
// h written as bf16 (ushort4 stores).
// ---------------------------------------------------------------------------
template <int COUT, int Hh, int NPT>
__global__ __launch_bounds__(256) void transform_kernel(
    const float* __restrict__ xin, const float* __restrict__ W,
    const float* __restrict__ a_src, const float* __restrict__ a_dst,
    unsigned short* __restrict__ hout, float* __restrict__ alsrc,
    float* __restrict__ aldst, int N)
{
    constexpr int JT = COUT / 4;          // threads per node-group: 32 or 8
    constexpr int GROUPS = 256 / JT;      // node-groups per block: 8 or 32
    constexpr int NB = GROUPS * NPT;      // nodes per block
    constexpr int PAD = 4;                // floats; +16B to break b128 conflicts
    __shared__ __align__(16) float xs[NB][128 + PAD];

    const int node0 = blockIdx.x * NB;
    const int total4 = NB * 32;           // float4s to stage
    const int lim4 = (N - node0) * 32;
    const float4* src4 = (const float4*)(xin + (size_t)node0 * 128);
    for (int i = threadIdx.x; i < total4; i += 256) {
        int row = i >> 5, col = i & 31;
        float4 v = (i < lim4) ? src4[i] : make_float4(0.f, 0.f, 0.f, 0.f);
        *(float4*)&xs[row][col << 2] = v;
    }
    __syncthreads();

    const int jt = threadIdx.x % JT;      // 4-wide column group
    const int g  = threadIdx.x / JT;
    const int j4 = jt * 4;

    float4 acc[NPT];
#pragma unroll
    for (int m = 0; m < NPT; ++m) acc[m] = make_float4(0.f, 0.f, 0.f, 0.f);

    const float4* Wf4 = (const float4*)W;   // Wf4[k*JT + jt] = W[k][j4..j4+3]
    for (int k4 = 0; k4 < 32; ++k4) {
        float4 w0 = Wf4[(4 * k4 + 0) * JT + jt];
        float4 w1 = Wf4[(4 * k4 + 1) * JT + jt];
        float4 w2 = Wf4[(4 * k4 + 2) * JT + jt];
        float4 w3 = Wf4[(4 * k4 + 3) * JT + jt];
#pragma unroll
        for (int m = 0; m < NPT; ++m) {
            float4 xv = *(const float4*)&xs[g * NPT + m][k4 << 2];
            acc[m].x += xv.x * w0.x + xv.y * w1.x + xv.z * w2.x + xv.w * w3.x;
            acc[m].y += xv.x * w0.y + xv.y * w1.y + xv.z * w2.y + xv.w * w3.y;
            acc[m].z += xv.x * w0.z + xv.y * w1.z + xv.z * w2.z + xv.w * w3.z;
            acc[m].w += xv.x * w0.w + xv.y * w1.w + xv.z * w2.w + xv.w * w3.w;
        }
    }

    const float4 as4 = ((const float4*)a_src)[jt];
    const float4 ad4 = ((const float4*)a_dst)[jt];
    const int hh = j4 >> 5;               // head of this thread's 4 columns

#pragma unroll
    for (int m = 0; m < NPT; ++m) {
        int n = node0 + g * NPT + m;
        float4 v = acc[m];
        float sv = v.x * as4.x + v.y * as4.y + v.z * as4.z + v.w * as4.w;
        float dv = v.x * ad4.x + v.y * ad4.y + v.z * ad4.z + v.w * ad4.w;
#pragma unroll
        for (int off = 4; off >= 1; off >>= 1) {   // 8 threads per head
            sv += __shfl_xor(sv, off);
            dv += __shfl_xor(dv, off);
        }
        if (n < N) {
            ushort4 hp;
            hp.x = f2bf(v.x); hp.y = f2bf(v.y);
            hp.z = f2bf(v.z); hp.w = f2bf(v.w);
            ((ushort4*)(hout + (size_t)n * COUT))[jt] = hp;
            if ((jt & 7) == 0) {
                alsrc[n * Hh + hh] = sv;
                aldst[n * Hh + hh] = dv;
            }
        }
    }
}

// ---------------------------------------------------------------------------
// CSR build, bucket-local counting sort (64 dst nodes per bucket):
//   bin   : block-aggregated — LDS histogram over buckets, ONE padded global
//           atomic per (block,bucket) run reservation, LDS-cursor placement.
//   hist  : per-bucket LDS histogram -> deg[] (coalesced)
//   scan  : 3-pass multi-block exclusive scan of deg -> offsets
//   place : per-bucket LDS cursors seeded from offsets -> src_sorted
// ---------------------------------------------------------------------------
#define BKT_CAP 2048    // slots per bucket (E/N*64 ~= 1023 expected)
#define NBKT_MAX 1024   // supports N <= 65536
#define CH_BIN 8192     // edges per bin block

__global__ __launch_bounds__(256) void bin_kernel(
    const int* __restrict__ src, const int* __restrict__ dst,
    int* __restrict__ bcnt, unsigned int* __restrict__ tmp, int E, int nbkt)
{
    __shared__ int hist[NBKT_MAX];
    __shared__ int base[NBKT_MAX];
    const int e0 = blockIdx.x * CH_BIN;
    const int e1 = min(e0 + CH_BIN, E);

    for (int b = threadIdx.x; b < nbkt; b += 256) hist[b] = 0;
    __syncthreads();
    for (int e = e0 + threadIdx.x; e < e1; e += 256) {
        int d = __builtin_nontemporal_load(dst + e);
        atomicAdd(&hist[d >> 6], 1);
    }
    __syncthreads();
    for (int b = threadIdx.x; b < nbkt; b += 256) {
        int c = hist[b];
        base[b] = (c > 0) ? atomicAdd(&bcnt[b << 4], c) : 0;  // 64B-strided
        hist[b] = 0;                                          // reuse as cursor
    }
    __syncthreads();
    for (int e = e0 + threadIdx.x; e < e1; e += 256) {
        int d = __builtin_nontemporal_load(dst + e);
        int s = __builtin_nontemporal_load(src + e);
        int b = d >> 6;
        int pos = base[b] + atomicAdd(&hist[b], 1);
        if (pos < BKT_CAP)
            tmp[((size_t)b << 11) + pos] =
                ((unsigned int)s << 6) | (unsigned int)(d & 63);
    }
}

__global__ __launch_bounds__(256) void hist_kernel(
    const unsigned int* __restrict__ tmp, const int* __restrict__ bcnt,
    int* __restrict__ deg, int N)
{
    int b = blockIdx.x;
    __shared__ int hist[64];
    if (threadIdx.x < 64) hist[threadIdx.x] = 0;
    __syncthreads();
    int cnt = min(bcnt[b << 4], BKT_CAP);
    const unsigned int* tb = tmp + ((size_t)b << 11);
    for (int i = threadIdx.x; i < cnt; i += 256)
        atomicAdd(&hist[tb[i] & 63u], 1);
    __syncthreads();
    if (threadIdx.x < 64) {
        int node = (b << 6) + threadIdx.x;
        if (node < N) deg[node] = hist[threadIdx.x];
    }
}

__global__ __launch_bounds__(256) void block_sum_kernel(
    const int* __restrict__ deg, int* __restrict__ blocksums, int N)
{
    int base = blockIdx.x * 4096 + threadIdx.x * 16;
    int s = 0;
#pragma unroll
    for (int i = 0; i < 16; ++i) {
        int idx = base + i;
        if (idx < N) s += deg[idx];
    }
#pragma unroll
    for (int off = 1; off < 64; off <<= 1) s += __shfl_xor(s, off);
    __shared__ int wsum[4];
    if ((threadIdx.x & 63) == 0) wsum[threadIdx.x >> 6] = s;
    __syncthreads();
    if (threadIdx.x == 0)
        blocksums[blockIdx.x] = wsum[0] + wsum[1] + wsum[2] + wsum[3];
}

__global__ __launch_bounds__(64) void scan_sums_kernel(
    const int* __restrict__ blocksums, int* __restrict__ blockbase,
    int* __restrict__ total_out, int nb)
{
    int tid = threadIdx.x;
    int orig = (tid < nb) ? blocksums[tid] : 0;
    int v = orig;
#pragma unroll
    for (int off = 1; off < 64; off <<= 1) {
        int t = __shfl_up(v, off);
        if (tid >= off) v += t;
    }
    if (tid < nb) blockbase[tid] = v - orig;     // exclusive
    if (tid == nb - 1) *total_out = v;           // offsets[N]
}

__global__ __launch_bounds__(256) void scan_final_kernel(
    const int* __restrict__ deg, const int* __restrict__ blockbase,
    int* __restrict__ offsets, int N)
{
    int base = blockIdx.x * 4096 + threadIdx.x * 16;
    int v[16];
    int s = 0;
#pragma unroll
    for (int i = 0; i < 16; ++i) {
        int idx = base + i;
        v[i] = (idx < N) ? deg[idx] : 0;
        s += v[i];
    }
    int lane = threadIdx.x & 63, wid = threadIdx.x >> 6;
    int incl = s;
#pragma unroll
    for (int off = 1; off < 64; off <<= 1) {
        int t = __shfl_up(incl, off);
        if (lane >= off) incl += t;
    }
    __shared__ int wsum[4];
    if (lane == 63) wsum[wid] = incl;
    __syncthreads();
    int woff = 0;
    for (int i = 0; i < wid; ++i) woff += wsum[i];
    int run = blockbase[blockIdx.x] + woff + incl - s;  // thread-exclusive
#pragma unroll
    for (int i = 0; i < 16; ++i) {
        int idx = base + i;
        if (idx < N) offsets[idx] = run;
        run += v[i];
    }
}

__global__ __launch_bounds__(256) void place_kernel(
    const unsigned int* __restrict__ tmp, const int* __restrict__ bcnt,
    const int* __restrict__ offsets, int* __restrict__ src_sorted, int N)
{
    int b = blockIdx.x;
    __shared__ int cur[64];
    if (threadIdx.x < 64) {
        int node = (b << 6) + threadIdx.x;
        cur[threadIdx.x] = (node < N) ? offsets[node] : 0;
    }
    __syncthreads();
    int cnt = min(bcnt[b << 4], BKT_CAP);
    const unsigned int* tb = tmp + ((size_t)b << 11);
    for (int i = threadIdx.x; i < cnt; i += 256) {
        unsigned int p = tb[i];
        int pos = atomicAdd(&cur[p & 63u], 1);
        src_sorted[pos] = (int)(p >> 6);
    }
}

// ---------------------------------------------------------------------------
// Fused GAT aggregation (per-node gather, zero atomics), bf16 h:
// 4 channels per thread (one 8B load per edge/thread), TPN = HC/4 threads
// per node. Edge weights staged in LDS per chunk; denominator in-register;
// self-loop folded analytically; divide, +bias, (ELU).
// ---------------------------------------------------------------------------
template <int Hh, int Cc, bool DO_ELU>
__global__ __launch_bounds__(256) void gat_agg_kernel(
    const int* __restrict__ offsets, const int* __restrict__ src_sorted,
    const unsigned short* __restrict__ h, const float* __restrict__ alsrc,
    const float* __restrict__ aldst, const float* __restrict__ bias,
    float* __restrict__ outf, int N)
{
    constexpr int HC  = Hh * Cc;         // 128 or 32
    constexpr int TPN = HC / 4;          // threads per node: 32 or 8
    constexpr int NPB = 256 / TPN;       // nodes per block: 8 or 32
    constexpr int CHUNK = 64;
    __shared__ int   s_src[NPB][CHUNK];
    __shared__ __align__(16) float s_w[NPB][CHUNK][Hh];
    __shared__ int   s_nch[NPB];

    const int g  = threadIdx.x / TPN;
    const int lt = threadIdx.x % TPN;
    const int n  = blockIdx.x * NPB + g;
    const bool valid = n < N;

    int off0 = 0, deg = 0;
    if (valid) { off0 = offsets[n]; deg = offsets[n + 1] - off0; }
    if (lt == 0) s_nch[g] = (deg + CHUNK - 1) / CHUNK;
    __syncthreads();
    int maxch = 0;
#pragma unroll
    for (int i = 0; i < NPB; ++i) maxch = max(maxch, s_nch[i]);

    const int hh = lt / (Cc / 4);        // head of this thread's 4 channels
    float adv[Hh];
    if (valid) {
        if constexpr (Hh == 4) {
            float4 t = ((const float4*)aldst)[n];
            adv[0] = t.x; adv[1] = t.y; adv[2] = t.z; adv[3] = t.w;
        } else {
            adv[0] = aldst[n];
        }
    }

    const uint2* h2 = (const uint2*)h;   // one row = TPN uint2 (8B = 4 ch)

    float a0 = 0.f, a1 = 0.f, a2 = 0.f, a3 = 0.f, den = 0.f;
    for (int ch = 0; ch < maxch; ++ch) {
        int base = ch * CHUNK;
        int cnt = deg - base;
        cnt = cnt < 0 ? 0 : (cnt > CHUNK ? CHUNK : cnt);
        __syncthreads();                 // LDS reuse fence
        for (int i = lt; i < cnt; i += TPN) {
            int s = src_sorted[off0 + base + i];
            s_src[g][i] = s;
            if constexpr (Hh == 4) {
                float4 av = ((const float4*)alsrc)[s];
                ((float4*)&s_w[g][i][0])[0] = make_float4(
                    __expf(lrelu(av.x + adv[0])), __expf(lrelu(av.y + adv[1])),
                    __expf(lrelu(av.z + adv[2])), __expf(lrelu(av.w + adv[3])));
            } else {
                s_w[g][i][0] = __expf(lrelu(alsrc[s] + adv[0]));
            }
        }
        __syncthreads();
        for (int i = 0; i < cnt; ++i) {
            int s = s_src[g][i];
            float w = s_w[g][i][hh];
            uint2 p = h2[(size_t)s * TPN + lt];
            a0 += w * bflo(p.x);
            a1 += w * bfhi(p.x);
            a2 += w * bflo(p.y);
            a3 += w * bfhi(p.y);
            den += w;
        }
    }

    if (valid) {
        float wself = __expf(lrelu(alsrc[n * Hh + hh] + adv[hh]));
        uint2 p = h2[(size_t)n * TPN + lt];
        a0 += wself * bflo(p.x);
        a1 += wself * bfhi(p.x);
        a2 += wself * bflo(p.y);
        a3 += wself * bfhi(p.y);
        den += wself + 1e-16f;
        float inv = 1.f / den;
        float4 bv = ((const float4*)bias)[lt];
        float4 o = make_float4(a0 * inv + bv.x, a1 * inv + bv.y,
                               a2 * inv + bv.z, a3 * inv + bv.w);
        if (DO_ELU) {
            o.x = o.x > 0.f ? o.x : __expf(o.x) - 1.f;
            o.y = o.y > 0.f ? o.y : __expf(o.y) - 1.f;
            o.z = o.z > 0.f ? o.z : __expf(o.z) - 1.f;
            o.w = o.w > 0.f ? o.w : __expf(o.w) - 1.f;
        }
        ((float4*)(outf + (size_t)n * HC))[lt] = o;
    }
}

// ---------------------------------------------------------------------------
// classification head: out[n,k] = h3[n,:] @ Wc[:,k] + bc[k]   (32 -> 2)
// ---------------------------------------------------------------------------
__global__ __launch_bounds__(256) void head_kernel(
    const float* __restrict__ h3, const float* __restrict__ Wc,
    const float* __restrict__ bc, float* __restrict__ out, int N)
{
    int t = blockIdx.x * 256 + threadIdx.x;
    int n = t / 2, k = t % 2;
    if (n >= N) return;
    float s = bc[k];
#pragma unroll
    for (int c = 0; c < 32; ++c) s += h3[(size_t)n * 32 + c] * Wc[c * 2 + k];
    out[(size_t)n * 2 + k] = s;
}

extern "C" void kernel_launch(void* const* d_in, const int* in_sizes, int n_in,
                              void* d_out, int out_size, void* d_ws, size_t ws_size,
                              hipStream_t stream)
{
    const float* x   = (const float*)d_in[0];
    const int*   ei  = (const int*)d_in[1];
    const float* W1  = (const float*)d_in[2];
    const float* a1s = (const float*)d_in[3];
    const float* a1d = (const float*)d_in[4];
    const float* b1  = (const float*)d_in[5];
    const float* W2  = (const float*)d_in[6];
    const float* a2s = (const float*)d_in[7];
    const float* a2d = (const float*)d_in[8];
    const float* b2  = (const float*)d_in[9];
    const float* W3  = (const float*)d_in[10];
    const float* a3s = (const float*)d_in[11];
    const float* a3d = (const float*)d_in[12];
    const float* b3  = (const float*)d_in[13];
    const float* Wc  = (const float*)d_in[14];
    const float* bc  = (const float*)d_in[15];

    const int N = in_sizes[0] / 128;
    const int E = in_sizes[1] / 2;
    const int* srcIdx = ei;
    const int* dstIdx = ei + E;

    const int NBKT = (N + 63) >> 6;                     // buckets of 64 dsts

    float* ws    = (float*)d_ws;
    float* fbuf  = ws;                                  // N*128 fp32
    float* alsrc = fbuf + (size_t)N * 128;              // N*4 (16B aligned)
    float* aldst = alsrc + (size_t)N * 4;               // N*4
    unsigned short* hbuf = (unsigned short*)(aldst + (size_t)N * 4); // N*128 bf16
    int* deg        = (int*)(hbuf + (size_t)N * 128);   // N
    int* offsets    = deg + N;                          // N+1
    int* src_sorted = offsets + N + 1;                  // E
    int* blocksums  = src_sorted + E;                   // 64
    int* blockbase  = blocksums + 64;                   // 64
    int* bcnt       = blockbase + 64;                   // NBKT*16 (64B-strided)
    unsigned int* tmp = (unsigned int*)(bcnt + (size_t)NBKT * 16); // NBKT*BKT_CAP

    float* node_out = (float*)d_out;                    // N*2
    float* link_out = node_out + (size_t)N * 2;         // N*32

    const int nb = (N + 4095) / 4096;                   // scan blocks (<=64)
    const int nbBin = (E + CH_BIN - 1) / CH_BIN;

    // ---------------- CSR build (dst-sorted), reused by all 3 layers --------
    hipMemsetAsync(bcnt, 0, (size_t)NBKT * 16 * sizeof(int), stream);
    bin_kernel<<<nbBin, 256, 0, stream>>>(srcIdx, dstIdx, bcnt, tmp, E, NBKT);
    hist_kernel<<<NBKT, 256, 0, stream>>>(tmp, bcnt, deg, N);
    block_sum_kernel<<<nb, 256, 0, stream>>>(deg, blocksums, N);
    scan_sums_kernel<<<1, 64, 0, stream>>>(blocksums, blockbase, offsets + N, nb);
    scan_final_kernel<<<nb, 256, 0, stream>>>(deg, blockbase, offsets, N);
    place_kernel<<<NBKT, 256, 0, stream>>>(tmp, bcnt, offsets, src_sorted, N);

    // ---------------- layer 1 (IN=128 -> H=4,C=32, concat, ELU) -------------
    transform_kernel<128, 4, 8><<<(N + 63) / 64, 256, 0, stream>>>(
        x, W1, a1s, a1d, hbuf, alsrc, aldst, N);
    gat_agg_kernel<4, 32, true><<<(N + 7) / 8, 256, 0, stream>>>(
        offsets, src_sorted, hbuf, alsrc, aldst, b1, fbuf, N);

    // ---------------- layer 2 (128 -> H=4,C=32, concat, ELU) ----------------
    transform_kernel<128, 4, 8><<<(N + 63) / 64, 256, 0, stream>>>(
        fbuf, W2, a2s, a2d, hbuf, alsrc, aldst, N);
    gat_agg_kernel<4, 32, true><<<(N + 7) / 8, 256, 0, stream>>>(
        offsets, src_sorted, hbuf, alsrc, aldst, b2, fbuf, N);

    // ---------------- layer 3 (128 -> H=1,C=32, no concat, no ELU) ----------
    transform_kernel<32, 1, 4><<<(N + 127) / 128, 256, 0, stream>>>(
        fbuf, W3, a3s, a3d, hbuf, alsrc, aldst, N);
    gat_agg_kernel<1, 32, false><<<(N + 31) / 32, 256, 0, stream>>>(
        offsets, src_sorted, hbuf, alsrc, aldst, b3, link_out, N);

    // ---------------- head: node_output = h3 @ Wc + bc ----------------------
    head_kernel<<<(N * 2 + 255) / 256, 256, 0, stream>>>(link_out, Wc, bc, node_out, N);
}

// Round 8
// 323.456 us; speedup vs baseline: 1.5877x; 1.0771x over previous
//
#include <hip/hip_runtime.h>
#include <math.h>

#define SLOPE 0.2f

__device__ __forceinline__ float lrelu(float x) { return x > 0.f ? x : SLOPE * x; }

// bf16 helpers (h is stored bf16 to halve gather traffic; error budget 1e-2)
__device__ __forceinline__ float bflo(unsigned int u) { return __uint_as_float(u << 16); }
__device__ __forceinline__ float bfhi(unsigned int u) { return __uint_as_float(u & 0xffff0000u); }
__device__ __forceinline__ unsigned short f2bf(float f) {   // round-nearest-even
    unsigned int u = __float_as_uint(f);
    unsigned int r = u + 0x7fffu + ((u >> 16) & 1u);
    return (unsigned short)(r >> 16);
}

// ---------------------------------------------------------------------------
// h = x @ W  (CIN=128), fused with attention logits.
// Register tile: 4 output channels x NPT nodes per thread (k4-vectorized:
// ds_read_b128 for x, dwordx4 for W, VALU-bound ~86% FMA density).
// ---------------------------------------------------------------------------
template <int COUT, int Hh, int NPT>
__global__ __launch_bounds__(256) void transform_kernel(
    const float* __restrict__ xin, const float* __restrict__ W,
    const float* __restrict__ a_src, const float* __restrict__ a_dst,
    unsigned short* __restrict__ hout, float* __restrict__ alsrc,
    float* __restrict__ aldst, int N)
{
    constexpr int JT = COUT / 4;          // threads per node-group: 32 or 8
    constexpr int GROUPS = 256 / JT;      // node-groups per block: 8 or 32
    constexpr int NB = GROUPS * NPT;      // nodes per block
    constexpr int PAD = 4;                // floats; +16B to break b128 conflicts
    __shared__ __align__(16) float xs[NB][128 + PAD];

    const int node0 = blockIdx.x * NB;
    const int total4 = NB * 32;           // float4s to stage
    const int lim4 = (N - node0) * 32;
    const float4* src4 = (const float4*)(xin + (size_t)node0 * 128);
    for (int i = threadIdx.x; i < total4; i += 256) {
        int row = i >> 5, col = i & 31;
        float4 v = (i < lim4) ? src4[i] : make_float4(0.f, 0.f, 0.f, 0.f);
        *(float4*)&xs[row][col << 2] = v;
    }
    __syncthreads();

    const int jt = threadIdx.x % JT;      // 4-wide column group
    const int g  = threadIdx.x / JT;
    const int j4 = jt * 4;

    float4 acc[NPT];
#pragma unroll
    for (int m = 0; m < NPT; ++m) acc[m] = make_float4(0.f, 0.f, 0.f, 0.f);

    const float4* Wf4 = (const float4*)W;   // Wf4[k*JT + jt] = W[k][j4..j4+3]
    for (int k4 = 0; k4 < 32; ++k4) {
        float4 w0 = Wf4[(4 * k4 + 0) * JT + jt];
        float4 w1 = Wf4[(4 * k4 + 1) * JT + jt];
        float4 w2 = Wf4[(4 * k4 + 2) * JT + jt];
        float4 w3 = Wf4[(4 * k4 + 3) * JT + jt];
#pragma unroll
        for (int m = 0; m < NPT; ++m) {
            float4 xv = *(const float4*)&xs[g * NPT + m][k4 << 2];
            acc[m].x += xv.x * w0.x + xv.y * w1.x + xv.z * w2.x + xv.w * w3.x;
            acc[m].y += xv.x * w0.y + xv.y * w1.y + xv.z * w2.y + xv.w * w3.y;
            acc[m].z += xv.x * w0.z + xv.y * w1.z + xv.z * w2.z + xv.w * w3.z;
            acc[m].w += xv.x * w0.w + xv.y * w1.w + xv.z * w2.w + xv.w * w3.w;
        }
    }

    const float4 as4 = ((const float4*)a_src)[jt];
    const float4 ad4 = ((const float4*)a_dst)[jt];
    const int hh = j4 >> 5;               // head of this thread's 4 columns

#pragma unroll
    for (int m = 0; m < NPT; ++m) {
        int n = node0 + g * NPT + m;
        float4 v = acc[m];
        float sv = v.x * as4.x + v.y * as4.y + v.z * as4.z + v.w * as4.w;
        float dv = v.x * ad4.x + v.y * ad4.y + v.z * ad4.z + v.w * ad4.w;
#pragma unroll
        for (int off = 4; off >= 1; off >>= 1) {   // 8 threads per head
            sv += __shfl_xor(sv, off);
            dv += __shfl_xor(dv, off);
        }
        if (n < N) {
            ushort4 hp;
            hp.x = f2bf(v.x); hp.y = f2bf(v.y);
            hp.z = f2bf(v.z); hp.w = f2bf(v.w);
            ((ushort4*)(hout + (size_t)n * COUT))[jt] = hp;
            if ((jt & 7) == 0) {
                alsrc[n * Hh + hh] = sv;
                aldst[n * Hh + hh] = dv;
            }
        }
    }
}

// ---------------------------------------------------------------------------
// CSR build, bucket-local counting sort (64 dst nodes per bucket):
//   bin   : block-aggregated — LDS histogram over buckets, ONE padded global
//           atomic per (block,bucket) run reservation, LDS-cursor placement.
//           1024 threads x 4096-edge chunks: 196 blocks x 16 waves so the
//           latency chain (load -> LDS atomic) is hidden (R6: 98 blocks x 4
//           waves = 3% occupancy was the bottleneck).
//   hist  : per-bucket LDS histogram -> deg[] (coalesced)
//   scan  : 3-pass multi-block exclusive scan of deg -> offsets
//   place : per-bucket LDS cursors seeded from offsets -> src_sorted
// ---------------------------------------------------------------------------
#define BKT_CAP 2048    // slots per bucket (E/N*64 ~= 1023 expected)
#define NBKT_MAX 1024   // supports N <= 65536
#define CH_BIN 4096     // edges per bin block

__global__ __launch_bounds__(1024) void bin_kernel(
    const int* __restrict__ src, const int* __restrict__ dst,
    int* __restrict__ bcnt, unsigned int* __restrict__ tmp, int E, int nbkt)
{
    __shared__ int hist[NBKT_MAX];
    __shared__ int base[NBKT_MAX];
    const int e0 = blockIdx.x * CH_BIN;
    const int e1 = min(e0 + CH_BIN, E);

    for (int b = threadIdx.x; b < nbkt; b += 1024) hist[b] = 0;
    __syncthreads();
    for (int e = e0 + threadIdx.x; e < e1; e += 1024) {
        int d = __builtin_nontemporal_load(dst + e);
        atomicAdd(&hist[d >> 6], 1);
    }
    __syncthreads();
    for (int b = threadIdx.x; b < nbkt; b += 1024) {
        int c = hist[b];
        base[b] = (c > 0) ? atomicAdd(&bcnt[b << 4], c) : 0;  // 64B-strided
        hist[b] = 0;                                          // reuse as cursor
    }
    __syncthreads();
    for (int e = e0 + threadIdx.x; e < e1; e += 1024) {
        int d = __builtin_nontemporal_load(dst + e);
        int s = __builtin_nontemporal_load(src + e);
        int b = d >> 6;
        int pos = base[b] + atomicAdd(&hist[b], 1);
        if (pos < BKT_CAP)
            tmp[((size_t)b << 11) + pos] =
                ((unsigned int)s << 6) | (unsigned int)(d & 63);
    }
}

__global__ __launch_bounds__(256) void hist_kernel(
    const unsigned int* __restrict__ tmp, const int* __restrict__ bcnt,
    int* __restrict__ deg, int N)
{
    int b = blockIdx.x;
    __shared__ int hist[64];
    if (threadIdx.x < 64) hist[threadIdx.x] = 0;
    __syncthreads();
    int cnt = min(bcnt[b << 4], BKT_CAP);
    const unsigned int* tb = tmp + ((size_t)b << 11);
    for (int i = threadIdx.x; i < cnt; i += 256)
        atomicAdd(&hist[tb[i] & 63u], 1);
    __syncthreads();
    if (threadIdx.x < 64) {
        int node = (b << 6) + threadIdx.x;
        if (node < N) deg[node] = hist[threadIdx.x];
    }
}

__global__ __launch_bounds__(256) void block_sum_kernel(
    const int* __restrict__ deg, int* __restrict__ blocksums, int N)
{
    int base = blockIdx.x * 4096 + threadIdx.x * 16;
    int s = 0;
#pragma unroll
    for (int i = 0; i < 16; ++i) {
        int idx = base + i;
        if (idx < N) s += deg[idx];
    }
#pragma unroll
    for (int off = 1; off < 64; off <<= 1) s += __shfl_xor(s, off);
    __shared__ int wsum[4];
    if ((threadIdx.x & 63) == 0) wsum[threadIdx.x >> 6] = s;
    __syncthreads();
    if (threadIdx.x == 0)
        blocksums[blockIdx.x] = wsum[0] + wsum[1] + wsum[2] + wsum[3];
}

__global__ __launch_bounds__(64) void scan_sums_kernel(
    const int* __restrict__ blocksums, int* __restrict__ blockbase,
    int* __restrict__ total_out, int nb)
{
    int tid = threadIdx.x;
    int orig = (tid < nb) ? blocksums[tid] : 0;
    int v = orig;
#pragma unroll
    for (int off = 1; off < 64; off <<= 1) {
        int t = __shfl_up(v, off);
        if (tid >= off) v += t;
    }
    if (tid < nb) blockbase[tid] = v - orig;     // exclusive
    if (tid == nb - 1) *total_out = v;           // offsets[N]
}

__global__ __launch_bounds__(256) void scan_final_kernel(
    const int* __restrict__ deg, const int* __restrict__ blockbase,
    int* __restrict__ offsets, int N)
{
    int base = blockIdx.x * 4096 + threadIdx.x * 16;
    int v[16];
    int s = 0;
#pragma unroll
    for (int i = 0; i < 16; ++i) {
        int idx = base + i;
        v[i] = (idx < N) ? deg[idx] : 0;
        s += v[i];
    }
    int lane = threadIdx.x & 63, wid = threadIdx.x >> 6;
    int incl = s;
#pragma unroll
    for (int off = 1; off < 64; off <<= 1) {
        int t = __shfl_up(incl, off);
        if (lane >= off) incl += t;
    }
    __shared__ int wsum[4];
    if (lane == 63) wsum[wid] = incl;
    __syncthreads();
    int woff = 0;
    for (int i = 0; i < wid; ++i) woff += wsum[i];
    int run = blockbase[blockIdx.x] + woff + incl - s;  // thread-exclusive
#pragma unroll
    for (int i = 0; i < 16; ++i) {
        int idx = base + i;
        if (idx < N) offsets[idx] = run;
        run += v[i];
    }
}

__global__ __launch_bounds__(256) void place_kernel(
    const unsigned int* __restrict__ tmp, const int* __restrict__ bcnt,
    const int* __restrict__ offsets, int* __restrict__ src_sorted, int N)
{
    int b = blockIdx.x;
    __shared__ int cur[64];
    if (threadIdx.x < 64) {
        int node = (b << 6) + threadIdx.x;
        cur[threadIdx.x] = (node < N) ? offsets[node] : 0;
    }
    __syncthreads();
    int cnt = min(bcnt[b << 4], BKT_CAP);
    const unsigned int* tb = tmp + ((size_t)b << 11);
    for (int i = threadIdx.x; i < cnt; i += 256) {
        unsigned int p = tb[i];
        int pos = atomicAdd(&cur[p & 63u], 1);
        src_sorted[pos] = (int)(p >> 6);
    }
}

// ---------------------------------------------------------------------------
// Fused GAT aggregation (per-node gather, zero atomics), bf16 h:
// 4 channels per thread (one 8B load per edge/thread), TPN = HC/4 threads
// per node. Edge weights staged in LDS per chunk; denominator in-register;
// self-loop folded analytically; divide, +bias, (ELU).
// ---------------------------------------------------------------------------
template <int Hh, int Cc, bool DO_ELU>
__global__ __launch_bounds__(256) void gat_agg_kernel(
    const int* __restrict__ offsets, const int* __restrict__ src_sorted,
    const unsigned short* __restrict__ h, const float* __restrict__ alsrc,
    const float* __restrict__ aldst, const float* __restrict__ bias,
    float* __restrict__ outf, int N)
{
    constexpr int HC  = Hh * Cc;         // 128 or 32
    constexpr int TPN = HC / 4;          // threads per node: 32 or 8
    constexpr int NPB = 256 / TPN;       // nodes per block: 8 or 32
    constexpr int CHUNK = 64;
    __shared__ int   s_src[NPB][CHUNK];
    __shared__ __align__(16) float s_w[NPB][CHUNK][Hh];
    __shared__ int   s_nch[NPB];

    const int g  = threadIdx.x / TPN;
    const int lt = threadIdx.x % TPN;
    const int n  = blockIdx.x * NPB + g;
    const bool valid = n < N;

    int off0 = 0, deg = 0;
    if (valid) { off0 = offsets[n]; deg = offsets[n + 1] - off0; }
    if (lt == 0) s_nch[g] = (deg + CHUNK - 1) / CHUNK;
    __syncthreads();
    int maxch = 0;
#pragma unroll
    for (int i = 0; i < NPB; ++i) maxch = max(maxch, s_nch[i]);

    const int hh = lt / (Cc / 4);        // head of this thread's 4 channels
    float adv[Hh];
    if (valid) {
        if constexpr (Hh == 4) {
            float4 t = ((const float4*)aldst)[n];
            adv[0] = t.x; adv[1] = t.y; adv[2] = t.z; adv[3] = t.w;
        } else {
            adv[0] = aldst[n];
        }
    }

    const uint2* h2 = (const uint2*)h;   // one row = TPN uint2 (8B = 4 ch)

    float a0 = 0.f, a1 = 0.f, a2 = 0.f, a3 = 0.f, den = 0.f;
    for (int ch = 0; ch < maxch; ++ch) {
        int base = ch * CHUNK;
        int cnt = deg - base;
        cnt = cnt < 0 ? 0 : (cnt > CHUNK ? CHUNK : cnt);
        __syncthreads();                 // LDS reuse fence
        for (int i = lt; i < cnt; i += TPN) {
            int s = src_sorted[off0 + base + i];
            s_src[g][i] = s;
            if constexpr (Hh == 4) {
                float4 av = ((const float4*)alsrc)[s];
                ((float4*)&s_w[g][i][0])[0] = make_float4(
                    __expf(lrelu(av.x + adv[0])), __expf(lrelu(av.y + adv[1])),
                    __expf(lrelu(av.z + adv[2])), __expf(lrelu(av.w + adv[3])));
            } else {
                s_w[g][i][0] = __expf(lrelu(alsrc[s] + adv[0]));
            }
        }
        __syncthreads();
        for (int i = 0; i < cnt; ++i) {
            int s = s_src[g][i];
            float w = s_w[g][i][hh];
            uint2 p = h2[(size_t)s * TPN + lt];
            a0 += w * bflo(p.x);
            a1 += w * bfhi(p.x);
            a2 += w * bflo(p.y);
            a3 += w * bfhi(p.y);
            den += w;
        }
    }

    if (valid) {
        float wself = __expf(lrelu(alsrc[n * Hh + hh] + adv[hh]));
        uint2 p = h2[(size_t)n * TPN + lt];
        a0 += wself * bflo(p.x);
        a1 += wself * bfhi(p.x);
        a2 += wself * bflo(p.y);
        a3 += wself * bfhi(p.y);
        den += wself + 1e-16f;
        float inv = 1.f / den;
        float4 bv = ((const float4*)bias)[lt];
        float4 o = make_float4(a0 * inv + bv.x, a1 * inv + bv.y,
                               a2 * inv + bv.z, a3 * inv + bv.w);
        if (DO_ELU) {
            o.x = o.x > 0.f ? o.x : __expf(o.x) - 1.f;
            o.y = o.y > 0.f ? o.y : __expf(o.y) - 1.f;
            o.z = o.z > 0.f ? o.z : __expf(o.z) - 1.f;
            o.w = o.w > 0.f ? o.w : __expf(o.w) - 1.f;
        }
        ((float4*)(outf + (size_t)n * HC))[lt] = o;
    }
}

// ---------------------------------------------------------------------------
// classification head: out[n,k] = h3[n,:] @ Wc[:,k] + bc[k]   (32 -> 2)
// ---------------------------------------------------------------------------
__global__ __launch_bounds__(256) void head_kernel(
    const float* __restrict__ h3, const float* __restrict__ Wc,
    const float* __restrict__ bc, float* __restrict__ out, int N)
{
    int t = blockIdx.x * 256 + threadIdx.x;
    int n = t / 2, k = t % 2;
    if (n >= N) return;
    float s = bc[k];
#pragma unroll
    for (int c = 0; c < 32; ++c) s += h3[(size_t)n * 32 + c] * Wc[c * 2 + k];
    out[(size_t)n * 2 + k] = s;
}

extern "C" void kernel_launch(void* const* d_in, const int* in_sizes, int n_in,
                              void* d_out, int out_size, void* d_ws, size_t ws_size,
                              hipStream_t stream)
{
    const float* x   = (const float*)d_in[0];
    const int*   ei  = (const int*)d_in[1];
    const float* W1  = (const float*)d_in[2];
    const float* a1s = (const float*)d_in[3];
    const float* a1d = (const float*)d_in[4];
    const float* b1  = (const float*)d_in[5];
    const float* W2  = (const float*)d_in[6];
    const float* a2s = (const float*)d_in[7];
    const float* a2d = (const float*)d_in[8];
    const float* b2  = (const float*)d_in[9];
    const float* W3  = (const float*)d_in[10];
    const float* a3s = (const float*)d_in[11];
    const float* a3d = (const float*)d_in[12];
    const float* b3  = (const float*)d_in[13];
    const float* Wc  = (const float*)d_in[14];
    const float* bc  = (const float*)d_in[15];

    const int N = in_sizes[0] / 128;
    const int E = in_sizes[1] / 2;
    const int* srcIdx = ei;
    const int* dstIdx = ei + E;

    const int NBKT = (N + 63) >> 6;                     // buckets of 64 dsts

    float* ws    = (float*)d_ws;
    float* fbuf  = ws;                                  // N*128 fp32
    float* alsrc = fbuf + (size_t)N * 128;              // N*4 (16B aligned)
    float* aldst = alsrc + (size_t)N * 4;               // N*4
    unsigned short* hbuf = (unsigned short*)(aldst + (size_t)N * 4); // N*128 bf16
    int* deg        = (int*)(hbuf + (size_t)N * 128);   // N
    int* offsets    = deg + N;                          // N+1
    int* src_sorted = offsets + N + 1;                  // E
    int* blocksums  = src_sorted + E;                   // 64
    int* blockbase  = blocksums + 64;                   // 64
    int* bcnt       = blockbase + 64;                   // NBKT*16 (64B-strided)
    unsigned int* tmp = (unsigned int*)(bcnt + (size_t)NBKT * 16); // NBKT*BKT_CAP

    float* node_out = (float*)d_out;                    // N*2
    float* link_out = node_out + (size_t)N * 2;         // N*32

    const int nb = (N + 4095) / 4096;                   // scan blocks (<=64)
    const int nbBin = (E + CH_BIN - 1) / CH_BIN;

    // ---------------- CSR build (dst-sorted), reused by all 3 layers --------
    hipMemsetAsync(bcnt, 0, (size_t)NBKT * 16 * sizeof(int), stream);
    bin_kernel<<<nbBin, 1024, 0, stream>>>(srcIdx, dstIdx, bcnt, tmp, E, NBKT);
    hist_kernel<<<NBKT, 256, 0, stream>>>(tmp, bcnt, deg, N);
    block_sum_kernel<<<nb, 256, 0, stream>>>(deg, blocksums, N);
    scan_sums_kernel<<<1, 64, 0, stream>>>(blocksums, blockbase, offsets + N, nb);
    scan_final_kernel<<<nb, 256, 0, stream>>>(deg, blockbase, offsets, N);
    place_kernel<<<NBKT, 256, 0, stream>>>(tmp, bcnt, offsets, src_sorted, N);

    // ---------------- layer 1 (IN=128 -> H=4,C=32, concat, ELU) -------------
    transform_kernel<128, 4, 8><<<(N + 63) / 64, 256, 0, stream>>>(
        x, W1, a1s, a1d, hbuf, alsrc, aldst, N);
    gat_agg_kernel<4, 32, true><<<(N + 7) / 8, 256, 0, stream>>>(
        offsets, src_sorted, hbuf, alsrc, aldst, b1, fbuf, N);

    // ---------------- layer 2 (128 -> H=4,C=32, concat, ELU) ----------------
    transform_kernel<128, 4, 8><<<(N + 63) / 64, 256, 0, stream>>>(
        fbuf, W2, a2s, a2d, hbuf, alsrc, aldst, N);
    gat_agg_kernel<4, 32, true><<<(N + 7) / 8, 256, 0, stream>>>(
        offsets, src_sorted, hbuf, alsrc, aldst, b2, fbuf, N);

    // ---------------- layer 3 (128 -> H=1,C=32, no concat, no ELU) ----------
    transform_kernel<32, 1, 4><<<(N + 127) / 128, 256, 0, stream>>>(
        fbuf, W3, a3s, a3d, hbuf, alsrc, aldst, N);
    gat_agg_kernel<1, 32, false><<<(N + 31) / 32, 256, 0, stream>>>(
        offsets, src_sorted, hbuf, alsrc, aldst, b3, link_out, N);

    // ---------------- head: node_output = h3 @ Wc + bc ----------------------
    head_kernel<<<(N * 2 + 255) / 256, 256, 0, stream>>>(link_out, Wc, bc, node_out, N);
}